// Round 5
// baseline (407.969 us; speedup 1.0000x reference)
//
#include <hip/hip_runtime.h>
#include <hip/hip_bf16.h>
#include <math.h>

#define NNODES 50000
#define NEDGE 625000
#define RREL 16
#define SCAN_NB 196   // ceil(50000/256)

typedef __attribute__((ext_vector_type(8))) short short8;
typedef __attribute__((ext_vector_type(4))) float f32x4;

__device__ __forceinline__ float bfu(ushort u) {
  return __uint_as_float(((unsigned)u) << 16);
}
__device__ __forceinline__ ushort f2b(float f) {
  __hip_bfloat16 h = __float2bfloat16(f);
  return *(ushort*)&h;
}

// ---------------- weight prep: bf16, B stored transposed (N x K, K contiguous) ----
__global__ __launch_bounds__(256) void prep_weights(
    const float* __restrict__ ipw, const float* __restrict__ opw,
    const float* __restrict__ w1, const float* __restrict__ root1,
    const float* __restrict__ w2, const float* __restrict__ root2,
    __hip_bfloat16* __restrict__ BTqkv, __hip_bfloat16* __restrict__ BTout,
    __hip_bfloat16* __restrict__ BT1, __hip_bfloat16* __restrict__ BT2) {
  int i = blockIdx.x * 256 + threadIdx.x;
  if (i < 49152) {
    BTqkv[i] = __float2bfloat16(ipw[i]);
  } else if (i < 65536) {
    int j = i - 49152;
    BTout[j] = __float2bfloat16(opw[j]);
  } else if (i < 65536 + 139264) {
    int j = i - 65536; int c = j / 128, k = j % 128;
    float v;
    if (c < 64) v = root1[k * 64 + c];
    else { int r = (c - 64) >> 6, o = (c - 64) & 63; v = w1[r * 8192 + k * 64 + o]; }
    BT1[j] = __float2bfloat16(v);
  } else if (i < 65536 + 139264 + 34816) {
    int j = i - 65536 - 139264; int c = j / 64, k = j % 64;
    float v;
    if (c < 32) v = root2[k * 32 + c];
    else { int r = (c - 32) >> 5, o = (c - 32) & 31; v = w2[r * 2048 + k * 32 + o]; }
    BT2[j] = __float2bfloat16(v);
  }
}

// ---------------- bf16 MFMA GEMM: C[M,N] = A[M,K] @ BT[N,K]^T (+bias) -------------
// 128x128 tile, 4 waves. A staged in LDS (f32 converted on the fly); B read
// DIRECTLY from global (L2-resident weights) into registers. C staged in padded
// LDS for coalesced int4 stores. LDS = 34.8KB -> 4 blocks/CU.
template <int K, bool AF32>
__global__ __launch_bounds__(256, 4) void gemm_mfma(
    const void* __restrict__ Av, const __hip_bfloat16* __restrict__ BT,
    const float* __restrict__ bias, __hip_bfloat16* __restrict__ C,
    int M, int Mq, int N, int lda, int ldc) {
  constexpr int CPR = K / 8;  // 16B (8-elem) chunks per row
  __shared__ ushort smem[128 * 136];  // A panel (128*K) / padded C staging
  ushort* As = smem;
  const int t = threadIdx.x;
  const long row0 = (long)blockIdx.x * 128;
  const int col0 = blockIdx.y * 128;
  const int Meff = (blockIdx.y == 0) ? Mq : M;
  if (row0 >= Meff) return;

#pragma unroll
  for (int c = t; c < 128 * CPR; c += 256) {
    int r = c / CPR, cc = c % CPR;
    long gm = row0 + r;
    int4 v = make_int4(0, 0, 0, 0);
    if (gm < Meff) {
      if constexpr (AF32) {
        const float* ap = (const float*)Av + gm * lda + cc * 8;
        float4 f0 = *(const float4*)ap;
        float4 f1 = *(const float4*)(ap + 4);
        v.x = (int)f2b(f0.x) | ((int)f2b(f0.y) << 16);
        v.y = (int)f2b(f0.z) | ((int)f2b(f0.w) << 16);
        v.z = (int)f2b(f1.x) | ((int)f2b(f1.y) << 16);
        v.w = (int)f2b(f1.z) | ((int)f2b(f1.w) << 16);
      } else {
        v = *(const int4*)((const ushort*)Av + gm * lda + cc * 8);
      }
    }
    *(int4*)(As + r * K + ((cc ^ (r & 7)) * 8)) = v;
  }
  __syncthreads();

  const int lane = t & 63, w = t >> 6;
  const int wr = (w >> 1) * 64, wc = (w & 1) * 64;
  const int lrow = lane & 15, lk = lane >> 4;

  // B fragment base pointers (direct global, row-clamped; bad cols dropped at store)
  const ushort* bp[4];
#pragma unroll
  for (int j = 0; j < 4; j++) {
    int gn = col0 + wc + j * 16 + lrow;
    if (gn > N - 1) gn = N - 1;
    bp[j] = (const ushort*)BT + (long)gn * K + lk * 8;
  }

  f32x4 acc[4][4];
#pragma unroll
  for (int i = 0; i < 4; i++)
#pragma unroll
    for (int j = 0; j < 4; j++) acc[i][j] = (f32x4){0.f, 0.f, 0.f, 0.f};

#pragma unroll
  for (int k0 = 0; k0 < K; k0 += 32) {
    const int cb = k0 / 8 + lk;
    short8 af[4], bfr[4];
#pragma unroll
    for (int j = 0; j < 4; j++) bfr[j] = *(const short8*)(bp[j] + k0);
#pragma unroll
    for (int i = 0; i < 4; i++) {
      int ra = wr + i * 16 + lrow;
      af[i] = *(const short8*)(As + ra * K + ((cb ^ (ra & 7)) * 8));
    }
#pragma unroll
    for (int i = 0; i < 4; i++)
#pragma unroll
      for (int j = 0; j < 4; j++)
        acc[i][j] = __builtin_amdgcn_mfma_f32_16x16x32_bf16(af[i], bfr[j], acc[i][j], 0, 0, 0);
  }

  // ---- epilogue: stage bf16 C-tile in padded LDS, then coalesced int4 stores ----
  __syncthreads();
  ushort* Cs = smem;  // stride 136 (conflict-free write)
#pragma unroll
  for (int j = 0; j < 4; j++) {
    int coll = wc + j * 16 + lrow;
    int bc = col0 + coll; if (bc > N - 1) bc = N - 1;
    float bv = bias ? bias[bc] : 0.f;
#pragma unroll
    for (int i = 0; i < 4; i++) {
      int rbase = wr + i * 16 + lk * 4;
#pragma unroll
      for (int q = 0; q < 4; q++)
        Cs[(rbase + q) * 136 + coll] = f2b(acc[i][j][q] + bv);
    }
  }
  __syncthreads();
#pragma unroll
  for (int idx = t; idx < 128 * 16; idx += 256) {
    int r = idx >> 4, k = idx & 15;
    long gm = row0 + r;
    int col = col0 + k * 8;
    if (gm < Meff && col < N)
      *(int4*)((ushort*)C + gm * ldc + col) = *(const int4*)(Cs + r * 136 + k * 8);
  }
}

// ---------------- attention (only l=0 of output needed) ---------------------------
// qkv: row (l*NNODES+n), cols: [0,128)=q, [128,256)=k, [256,384)=v, ld=384
__global__ __launch_bounds__(256) void attn_kernel(
    const __hip_bfloat16* __restrict__ qkv, __hip_bfloat16* __restrict__ o0) {
  int t = threadIdx.x;
  int n = blockIdx.x * 2 + (t >> 7);
  int ch = t & 127;
  float q = __bfloat162float(qkv[(size_t)n * 384 + ch]);
  float s[4];
#pragma unroll
  for (int m = 0; m < 4; m++) {
    float kk = __bfloat162float(qkv[(size_t)(m * NNODES + n) * 384 + 128 + ch]);
    float p = q * kk;
#pragma unroll
    for (int off = 16; off; off >>= 1) p += __shfl_xor(p, off);
    s[m] = p * 0.17677669529663687f;
  }
  float mx = fmaxf(fmaxf(s[0], s[1]), fmaxf(s[2], s[3]));
  float e[4], sum = 0.f;
#pragma unroll
  for (int m = 0; m < 4; m++) { e[m] = __expf(s[m] - mx); sum += e[m]; }
  float inv = 1.0f / sum;
  float out = 0.f;
#pragma unroll
  for (int m = 0; m < 4; m++)
    out += e[m] * inv * __bfloat162float(qkv[(size_t)(m * NNODES + n) * 384 + 256 + ch]);
  o0[(size_t)n * 128 + ch] = __float2bfloat16(out);
}

// ---------------- edge counts per (r, dst) ---------------------------------------
__global__ __launch_bounds__(256) void count_edges(
    const int* __restrict__ dst, const int* __restrict__ et, int* __restrict__ cnt) {
  int e = blockIdx.x * 256 + threadIdx.x;
  if (e < NEDGE) atomicAdd(&cnt[et[e] * NNODES + dst[e]], 1);
}

// ---------------- CSR build ------------------------------------------------------
__global__ __launch_bounds__(256) void scan1(
    const int* __restrict__ cnt, int* __restrict__ off, int* __restrict__ part) {
  int t = threadIdx.x, b = blockIdx.x;
  int i = b * 256 + t;
  int v = 0;
  if (i < NNODES) {
#pragma unroll
    for (int r = 0; r < RREL; r++) v += cnt[r * NNODES + i];
  }
  __shared__ int sm[256];
  sm[t] = v;
  __syncthreads();
#pragma unroll
  for (int o = 1; o < 256; o <<= 1) {
    int x = (t >= o) ? sm[t - o] : 0;
    __syncthreads();
    sm[t] += x;
    __syncthreads();
  }
  if (i < NNODES) off[i] = sm[t] - v;
  if (t == 255) part[b] = sm[t];
}

__global__ __launch_bounds__(256) void scan2(int* __restrict__ part) {
  int t = threadIdx.x;
  int v = (t < SCAN_NB) ? part[t] : 0;
  __shared__ int sm[256];
  sm[t] = v;
  __syncthreads();
#pragma unroll
  for (int o = 1; o < 256; o <<= 1) {
    int x = (t >= o) ? sm[t - o] : 0;
    __syncthreads();
    sm[t] += x;
    __syncthreads();
  }
  if (t < SCAN_NB) part[t] = sm[t] - v;
}

__global__ __launch_bounds__(256) void scan3(int* __restrict__ off, const int* __restrict__ part) {
  int i = blockIdx.x * 256 + threadIdx.x;
  if (i < NNODES) off[i] += part[blockIdx.x];
  if (i == 0) off[NNODES] = NEDGE;
}

__global__ __launch_bounds__(256) void scatter_edges(
    const int* __restrict__ src, const int* __restrict__ dst, const int* __restrict__ et,
    const int* __restrict__ cnt, const int* __restrict__ off,
    int* __restrict__ fill, unsigned* __restrict__ sorted, float* __restrict__ scales) {
  int e = blockIdx.x * 256 + threadIdx.x;
  if (e >= NEDGE) return;
  int d = dst[e], r = et[e], s = src[e];
  int pos = off[d] + atomicAdd(&fill[d], 1);
  sorted[pos] = (unsigned)s | ((unsigned)r << 16);
  scales[pos] = 1.0f / (float)cnt[r * NNODES + d];
}

// ---------------- fused layer1: root+bias + segmented mean-agg + relu -> bf16 -----
__global__ __launch_bounds__(256) void fused1(
    const int* __restrict__ off, const unsigned* __restrict__ sorted,
    const float* __restrict__ scales, const ushort* __restrict__ Y1,
    const float* __restrict__ b1, __hip_bfloat16* __restrict__ x1b) {
  int w = threadIdx.x >> 6, lane = threadIdx.x & 63;
  int d = blockIdx.x * 4 + w;
  int s0 = off[d], s1 = off[d + 1];
  float acc = bfu(Y1[(size_t)d * 1088 + lane]) + b1[lane];
  for (int i = s0; i < s1; i++) {
    unsigned p = sorted[i];
    acc += bfu(Y1[(size_t)(p & 0xFFFF) * 1088 + 64 + (p >> 16) * 64 + lane]) * scales[i];
  }
  x1b[(size_t)d * 64 + lane] = __float2bfloat16(fmaxf(acc, 0.f));
}

// ---------------- fused layer2: root+bias + agg + softmax -> out ------------------
__global__ __launch_bounds__(256) void fused2(
    const int* __restrict__ off, const unsigned* __restrict__ sorted,
    const float* __restrict__ scales, const ushort* __restrict__ Y2,
    const float* __restrict__ b2, float* __restrict__ out) {
  int w = threadIdx.x >> 6, lane = threadIdx.x & 63;
  int d = blockIdx.x * 4 + w;
  int j = lane & 31, half = lane >> 5;
  int s0 = off[d], s1 = off[d + 1];
  float acc = 0.f;
  for (int i = s0 + half; i < s1; i += 2) {
    unsigned p = sorted[i];
    acc += bfu(Y2[(size_t)(p & 0xFFFF) * 544 + 32 + (p >> 16) * 32 + j]) * scales[i];
  }
  acc += __shfl_xor(acc, 32);
  float v = acc + bfu(Y2[(size_t)d * 544 + j]) + b2[j];
  float mx = v;
#pragma unroll
  for (int o = 16; o; o >>= 1) mx = fmaxf(mx, __shfl_xor(mx, o));
  float e = __expf(v - mx);
  float sum = e;
#pragma unroll
  for (int o = 16; o; o >>= 1) sum += __shfl_xor(sum, o);
  if (half == 0) out[(size_t)d * 32 + j] = e / sum;
}

// =================================================================================
extern "C" void kernel_launch(void* const* d_in, const int* in_sizes, int n_in,
                              void* d_out, int out_size, void* d_ws, size_t ws_size,
                              hipStream_t stream) {
  (void)in_sizes; (void)n_in; (void)out_size; (void)ws_size;
  const float* emb   = (const float*)d_in[0];
  const float* ipw   = (const float*)d_in[1];
  const float* ipb   = (const float*)d_in[2];
  const float* opw   = (const float*)d_in[3];
  const float* opb   = (const float*)d_in[4];
  const float* w1    = (const float*)d_in[5];
  const float* root1 = (const float*)d_in[6];
  const float* b1    = (const float*)d_in[7];
  const float* w2    = (const float*)d_in[8];
  const float* root2 = (const float*)d_in[9];
  const float* b2    = (const float*)d_in[10];
  const int*   eidx  = (const int*)d_in[11];
  const int*   etype = (const int*)d_in[12];
  const int* srcp = eidx;
  const int* dstp = eidx + NEDGE;

  unsigned char* ws = (unsigned char*)d_ws;
  size_t off_b = 0;
  auto alloc = [&](size_t bytes) {
    unsigned char* p = ws + off_b;
    off_b += (bytes + 255) & ~(size_t)255;
    return p;
  };

  // Region R reused sequentially: qkv 153.6MB -> Y1 108.8MB -> Y2 54.4MB
  unsigned char* R = alloc(153600000);
  __hip_bfloat16* qkv = (__hip_bfloat16*)R;
  __hip_bfloat16* Y1  = (__hip_bfloat16*)R;
  __hip_bfloat16* Y2  = (__hip_bfloat16*)R;
  __hip_bfloat16* o0  = (__hip_bfloat16*)alloc(12800000);
  __hip_bfloat16* x0  = (__hip_bfloat16*)alloc(12800000);
  __hip_bfloat16* x1b = (__hip_bfloat16*)alloc(6400000);
  int*            cnt = (int*)alloc(3200000);
  int*            offs = (int*)alloc((NNODES + 1) * 4);
  int*            fill = (int*)alloc(NNODES * 4);
  int*            part = (int*)alloc(SCAN_NB * 4);
  unsigned*       sorted = (unsigned*)alloc(NEDGE * 4);
  float*          scales = (float*)alloc(NEDGE * 4);
  __hip_bfloat16* BTqkv = (__hip_bfloat16*)alloc(98304);
  __hip_bfloat16* BTout = (__hip_bfloat16*)alloc(32768);
  __hip_bfloat16* BT1   = (__hip_bfloat16*)alloc(278528);
  __hip_bfloat16* BT2   = (__hip_bfloat16*)alloc(69632);

  // 1) weight prep + CSR build
  prep_weights<<<dim3((241664 + 255) / 256), dim3(256), 0, stream>>>(
      ipw, opw, w1, root1, w2, root2, BTqkv, BTout, BT1, BT2);
  hipMemsetAsync(cnt, 0, (size_t)RREL * NNODES * sizeof(int), stream);
  hipMemsetAsync(fill, 0, (size_t)NNODES * sizeof(int), stream);
  count_edges<<<dim3((NEDGE + 255) / 256), dim3(256), 0, stream>>>(dstp, etype, cnt);
  scan1<<<dim3(SCAN_NB), dim3(256), 0, stream>>>(cnt, offs, part);
  scan2<<<dim3(1), dim3(256), 0, stream>>>(part);
  scan3<<<dim3(SCAN_NB), dim3(256), 0, stream>>>(offs, part);
  scatter_edges<<<dim3((NEDGE + 255) / 256), dim3(256), 0, stream>>>(
      srcp, dstp, etype, cnt, offs, fill, sorted, scales);

  // 2) QKV: (200000 x 128 f32) @ (128 x 384) -> qkv; Q strip only rows < 50000
  gemm_mfma<128, true><<<dim3(1563, 3), dim3(256), 0, stream>>>(
      emb, BTqkv, ipb, qkv, 200000, NNODES, 384, 128, 384);

  // 3) attention -> o0
  attn_kernel<<<dim3(25000), dim3(256), 0, stream>>>(qkv, o0);

  // 4) out_proj -> x0
  gemm_mfma<128, false><<<dim3(391, 1), dim3(256), 0, stream>>>(
      o0, BTout, opb, x0, NNODES, NNODES, 128, 128, 128);

  // 5) Y1 = x0 @ [root1 | W1_r]: (50000 x 128) @ (128 x 1088)
  gemm_mfma<128, false><<<dim3(391, 9), dim3(256), 0, stream>>>(
      x0, BT1, nullptr, Y1, NNODES, NNODES, 1088, 128, 1088);

  // 6) fused layer1 -> x1b
  fused1<<<dim3(NNODES / 4), dim3(256), 0, stream>>>(
      offs, sorted, scales, (const ushort*)Y1, b1, x1b);

  // 7) Y2 = x1b @ [root2 | W2_r]: (50000 x 64) @ (64 x 544)
  gemm_mfma<64, false><<<dim3(391, 5), dim3(256), 0, stream>>>(
      x1b, BT2, nullptr, Y2, NNODES, NNODES, 544, 64, 544);

  // 8) fused layer2 + softmax -> out
  fused2<<<dim3(NNODES / 4), dim3(256), 0, stream>>>(
      offs, sorted, scales, (const ushort*)Y2, b2, (float*)d_out);
}

// Round 6
// 371.280 us; speedup vs baseline: 1.0988x; 1.0988x over previous
//
#include <hip/hip_runtime.h>
#include <hip/hip_bf16.h>
#include <math.h>

#define NNODES 50000
#define NEDGE 625000
#define RREL 16
#define SCAN_NB 196   // ceil(50000/256)

typedef __attribute__((ext_vector_type(8))) short short8;
typedef __attribute__((ext_vector_type(4))) float f32x4;

__device__ __forceinline__ float bfu(ushort u) {
  return __uint_as_float(((unsigned)u) << 16);
}
__device__ __forceinline__ ushort f2b(float f) {
  __hip_bfloat16 h = __float2bfloat16(f);
  return *(ushort*)&h;
}

// ---------------- weight prep: bf16, B stored transposed (N x K, K contiguous) ----
__global__ __launch_bounds__(256) void prep_weights(
    const float* __restrict__ ipw, const float* __restrict__ opw,
    const float* __restrict__ w1, const float* __restrict__ root1,
    const float* __restrict__ w2, const float* __restrict__ root2,
    __hip_bfloat16* __restrict__ BTqkv, __hip_bfloat16* __restrict__ BTout,
    __hip_bfloat16* __restrict__ BT1, __hip_bfloat16* __restrict__ BT2) {
  int i = blockIdx.x * 256 + threadIdx.x;
  if (i < 49152) {
    BTqkv[i] = __float2bfloat16(ipw[i]);
  } else if (i < 65536) {
    int j = i - 49152;
    BTout[j] = __float2bfloat16(opw[j]);
  } else if (i < 65536 + 139264) {
    int j = i - 65536; int c = j / 128, k = j % 128;
    float v;
    if (c < 64) v = root1[k * 64 + c];
    else { int r = (c - 64) >> 6, o = (c - 64) & 63; v = w1[r * 8192 + k * 64 + o]; }
    BT1[j] = __float2bfloat16(v);
  } else if (i < 65536 + 139264 + 34816) {
    int j = i - 65536 - 139264; int c = j / 64, k = j % 64;
    float v;
    if (c < 32) v = root2[k * 32 + c];
    else { int r = (c - 32) >> 5, o = (c - 32) & 31; v = w2[r * 2048 + k * 32 + o]; }
    BT2[j] = __float2bfloat16(v);
  }
}

// ---------------- QKV GEMM: strip-loop, A staged ONCE per row panel ---------------
// A: emb f32 (200000 x 128). BT: 384x128 bf16. Strips: s=0 K cols[128,256),
// s=1 V cols[256,384), s=2 Q cols[0,128) only when row0 < NNODES.
__global__ __launch_bounds__(256) void qkv_gemm(
    const float* __restrict__ A, const __hip_bfloat16* __restrict__ BT,
    const float* __restrict__ bias, __hip_bfloat16* __restrict__ C) {
  __shared__ ushort As[128 * 128];   // 32KB
  __shared__ ushort Cs[128 * 136];   // 34.8KB padded C staging
  const int t = threadIdx.x;
  const long row0 = (long)blockIdx.x * 128;

  // stage A panel (f32 -> bf16), swizzled
#pragma unroll
  for (int c = t; c < 128 * 16; c += 256) {
    int r = c >> 4, cc = c & 15;
    long gm = row0 + r;
    int4 v = make_int4(0, 0, 0, 0);
    if (gm < 200000) {
      const float* ap = A + gm * 128 + cc * 8;
      float4 f0 = *(const float4*)ap;
      float4 f1 = *(const float4*)(ap + 4);
      v.x = (int)f2b(f0.x) | ((int)f2b(f0.y) << 16);
      v.y = (int)f2b(f0.z) | ((int)f2b(f0.w) << 16);
      v.z = (int)f2b(f1.x) | ((int)f2b(f1.y) << 16);
      v.w = (int)f2b(f1.z) | ((int)f2b(f1.w) << 16);
    }
    *(int4*)(As + r * 128 + ((cc ^ (r & 7)) * 8)) = v;
  }
  __syncthreads();

  const int lane = t & 63, w = t >> 6;
  const int wr = (w >> 1) * 64, wc = (w & 1) * 64;
  const int lrow = lane & 15, lk = lane >> 4;
  const int nstrips = (row0 < NNODES) ? 3 : 2;

  for (int s = 0; s < nstrips; s++) {
    const int col0 = (s == 2) ? 0 : 128 + s * 128;
    const long Meff = (s == 2) ? NNODES : 200000;

    const ushort* bp[4];
#pragma unroll
    for (int j = 0; j < 4; j++)
      bp[j] = (const ushort*)BT + (long)(col0 + wc + j * 16 + lrow) * 128 + lk * 8;

    f32x4 acc[4][4];
#pragma unroll
    for (int i = 0; i < 4; i++)
#pragma unroll
      for (int j = 0; j < 4; j++) acc[i][j] = (f32x4){0.f, 0.f, 0.f, 0.f};

#pragma unroll
    for (int k0 = 0; k0 < 128; k0 += 32) {
      const int cb = k0 / 8 + lk;
      short8 af[4], bfr[4];
#pragma unroll
      for (int j = 0; j < 4; j++) bfr[j] = *(const short8*)(bp[j] + k0);
#pragma unroll
      for (int i = 0; i < 4; i++) {
        int ra = wr + i * 16 + lrow;
        af[i] = *(const short8*)(As + ra * 128 + ((cb ^ (ra & 7)) * 8));
      }
#pragma unroll
      for (int i = 0; i < 4; i++)
#pragma unroll
        for (int j = 0; j < 4; j++)
          acc[i][j] = __builtin_amdgcn_mfma_f32_16x16x32_bf16(af[i], bfr[j], acc[i][j], 0, 0, 0);
    }

    __syncthreads();  // Cs free (prev strip's stores done)
#pragma unroll
    for (int j = 0; j < 4; j++) {
      int coll = wc + j * 16 + lrow;
      float bv = bias[col0 + coll];
#pragma unroll
      for (int i = 0; i < 4; i++) {
        int rbase = wr + i * 16 + lk * 4;
#pragma unroll
        for (int q = 0; q < 4; q++)
          Cs[(rbase + q) * 136 + coll] = f2b(acc[i][j][q] + bv);
      }
    }
    __syncthreads();
#pragma unroll
    for (int idx = t; idx < 128 * 16; idx += 256) {
      int r = idx >> 4, k = idx & 15;
      long gm = row0 + r;
      if (gm < Meff)
        *(int4*)((ushort*)C + gm * 384 + col0 + k * 8) = *(const int4*)(Cs + r * 136 + k * 8);
    }
  }
}

// ---------------- generic bf16 MFMA GEMM (B direct from global) -------------------
template <int K, bool AF32>
__global__ __launch_bounds__(256) void gemm_mfma(
    const void* __restrict__ Av, const __hip_bfloat16* __restrict__ BT,
    const float* __restrict__ bias, __hip_bfloat16* __restrict__ C,
    int M, int N, int lda, int ldc) {
  constexpr int CPR = K / 8;
  __shared__ ushort smem[128 * 136];
  ushort* As = smem;
  const int t = threadIdx.x;
  const long row0 = (long)blockIdx.x * 128;
  const int col0 = blockIdx.y * 128;
  if (row0 >= M) return;

#pragma unroll
  for (int c = t; c < 128 * CPR; c += 256) {
    int r = c / CPR, cc = c % CPR;
    long gm = row0 + r;
    int4 v = make_int4(0, 0, 0, 0);
    if (gm < M) {
      if constexpr (AF32) {
        const float* ap = (const float*)Av + gm * lda + cc * 8;
        float4 f0 = *(const float4*)ap;
        float4 f1 = *(const float4*)(ap + 4);
        v.x = (int)f2b(f0.x) | ((int)f2b(f0.y) << 16);
        v.y = (int)f2b(f0.z) | ((int)f2b(f0.w) << 16);
        v.z = (int)f2b(f1.x) | ((int)f2b(f1.y) << 16);
        v.w = (int)f2b(f1.z) | ((int)f2b(f1.w) << 16);
      } else {
        v = *(const int4*)((const ushort*)Av + gm * lda + cc * 8);
      }
    }
    *(int4*)(As + r * K + ((cc ^ (r & 7)) * 8)) = v;
  }
  __syncthreads();

  const int lane = t & 63, w = t >> 6;
  const int wr = (w >> 1) * 64, wc = (w & 1) * 64;
  const int lrow = lane & 15, lk = lane >> 4;

  const ushort* bp[4];
#pragma unroll
  for (int j = 0; j < 4; j++) {
    int gn = col0 + wc + j * 16 + lrow;
    if (gn > N - 1) gn = N - 1;
    bp[j] = (const ushort*)BT + (long)gn * K + lk * 8;
  }

  f32x4 acc[4][4];
#pragma unroll
  for (int i = 0; i < 4; i++)
#pragma unroll
    for (int j = 0; j < 4; j++) acc[i][j] = (f32x4){0.f, 0.f, 0.f, 0.f};

#pragma unroll
  for (int k0 = 0; k0 < K; k0 += 32) {
    const int cb = k0 / 8 + lk;
    short8 af[4], bfr[4];
#pragma unroll
    for (int j = 0; j < 4; j++) bfr[j] = *(const short8*)(bp[j] + k0);
#pragma unroll
    for (int i = 0; i < 4; i++) {
      int ra = wr + i * 16 + lrow;
      af[i] = *(const short8*)(As + ra * K + ((cb ^ (ra & 7)) * 8));
    }
#pragma unroll
    for (int i = 0; i < 4; i++)
#pragma unroll
      for (int j = 0; j < 4; j++)
        acc[i][j] = __builtin_amdgcn_mfma_f32_16x16x32_bf16(af[i], bfr[j], acc[i][j], 0, 0, 0);
  }

  __syncthreads();
  ushort* Cs = smem;
#pragma unroll
  for (int j = 0; j < 4; j++) {
    int coll = wc + j * 16 + lrow;
    int bc = col0 + coll; if (bc > N - 1) bc = N - 1;
    float bv = bias ? bias[bc] : 0.f;
#pragma unroll
    for (int i = 0; i < 4; i++) {
      int rbase = wr + i * 16 + lk * 4;
#pragma unroll
      for (int q = 0; q < 4; q++)
        Cs[(rbase + q) * 136 + coll] = f2b(acc[i][j][q] + bv);
    }
  }
  __syncthreads();
#pragma unroll
  for (int idx = t; idx < 128 * 16; idx += 256) {
    int r = idx >> 4, k = idx & 15;
    long gm = row0 + r;
    int col = col0 + k * 8;
    if (gm < M && col < N)
      *(int4*)((ushort*)C + gm * ldc + col) = *(const int4*)(Cs + r * 136 + k * 8);
  }
}

// ---------------- attention (only l=0 of output needed) ---------------------------
// qkv: row (l*NNODES+n), cols: [0,128)=q, [128,256)=k, [256,384)=v, ld=384
__global__ __launch_bounds__(256) void attn_kernel(
    const __hip_bfloat16* __restrict__ qkv, __hip_bfloat16* __restrict__ o0) {
  int t = threadIdx.x;
  int n = blockIdx.x * 2 + (t >> 7);
  int ch = t & 127;
  float q = __bfloat162float(qkv[(size_t)n * 384 + ch]);
  float s[4];
#pragma unroll
  for (int m = 0; m < 4; m++) {
    float kk = __bfloat162float(qkv[(size_t)(m * NNODES + n) * 384 + 128 + ch]);
    float p = q * kk;
#pragma unroll
    for (int off = 16; off; off >>= 1) p += __shfl_xor(p, off);
    s[m] = p * 0.17677669529663687f;
  }
  float mx = fmaxf(fmaxf(s[0], s[1]), fmaxf(s[2], s[3]));
  float e[4], sum = 0.f;
#pragma unroll
  for (int m = 0; m < 4; m++) { e[m] = __expf(s[m] - mx); sum += e[m]; }
  float inv = 1.0f / sum;
  float out = 0.f;
#pragma unroll
  for (int m = 0; m < 4; m++)
    out += e[m] * inv * __bfloat162float(qkv[(size_t)(m * NNODES + n) * 384 + 256 + ch]);
  o0[(size_t)n * 128 + ch] = __float2bfloat16(out);
}

// ---------------- edge counts per (r, dst) ---------------------------------------
__global__ __launch_bounds__(256) void count_edges(
    const int* __restrict__ dst, const int* __restrict__ et, int* __restrict__ cnt) {
  int e = blockIdx.x * 256 + threadIdx.x;
  if (e < NEDGE) atomicAdd(&cnt[et[e] * NNODES + dst[e]], 1);
}

// ---------------- CSR build ------------------------------------------------------
__global__ __launch_bounds__(256) void scan1(
    const int* __restrict__ cnt, int* __restrict__ off, int* __restrict__ part) {
  int t = threadIdx.x, b = blockIdx.x;
  int i = b * 256 + t;
  int v = 0;
  if (i < NNODES) {
#pragma unroll
    for (int r = 0; r < RREL; r++) v += cnt[r * NNODES + i];
  }
  __shared__ int sm[256];
  sm[t] = v;
  __syncthreads();
#pragma unroll
  for (int o = 1; o < 256; o <<= 1) {
    int x = (t >= o) ? sm[t - o] : 0;
    __syncthreads();
    sm[t] += x;
    __syncthreads();
  }
  if (i < NNODES) off[i] = sm[t] - v;
  if (t == 255) part[b] = sm[t];
}

__global__ __launch_bounds__(256) void scan2(int* __restrict__ part) {
  int t = threadIdx.x;
  int v = (t < SCAN_NB) ? part[t] : 0;
  __shared__ int sm[256];
  sm[t] = v;
  __syncthreads();
#pragma unroll
  for (int o = 1; o < 256; o <<= 1) {
    int x = (t >= o) ? sm[t - o] : 0;
    __syncthreads();
    sm[t] += x;
    __syncthreads();
  }
  if (t < SCAN_NB) part[t] = sm[t] - v;
}

__global__ __launch_bounds__(256) void scan3(int* __restrict__ off, const int* __restrict__ part) {
  int i = blockIdx.x * 256 + threadIdx.x;
  if (i < NNODES) off[i] += part[blockIdx.x];
  if (i == 0) off[NNODES] = NEDGE;
}

__global__ __launch_bounds__(256) void scatter_edges(
    const int* __restrict__ src, const int* __restrict__ dst, const int* __restrict__ et,
    const int* __restrict__ cnt, const int* __restrict__ off,
    int* __restrict__ fill, unsigned* __restrict__ sorted, float* __restrict__ scales) {
  int e = blockIdx.x * 256 + threadIdx.x;
  if (e >= NEDGE) return;
  int d = dst[e], r = et[e], s = src[e];
  int pos = off[d] + atomicAdd(&fill[d], 1);
  sorted[pos] = (unsigned)s | ((unsigned)r << 16);
  scales[pos] = 1.0f / (float)cnt[r * NNODES + d];
}

// ---------------- fused layer1: root+bias + segmented mean-agg + relu -> bf16 -----
__global__ __launch_bounds__(256) void fused1(
    const int* __restrict__ off, const unsigned* __restrict__ sorted,
    const float* __restrict__ scales, const ushort* __restrict__ Y1,
    const float* __restrict__ b1, __hip_bfloat16* __restrict__ x1b) {
  int w = threadIdx.x >> 6, lane = threadIdx.x & 63;
  int d = blockIdx.x * 4 + w;
  int s0 = off[d], s1 = off[d + 1];
  float acc = bfu(Y1[(size_t)d * 1088 + lane]) + b1[lane];
  for (int i = s0; i < s1; i++) {
    unsigned p = sorted[i];
    acc += bfu(Y1[(size_t)(p & 0xFFFF) * 1088 + 64 + (p >> 16) * 64 + lane]) * scales[i];
  }
  x1b[(size_t)d * 64 + lane] = __float2bfloat16(fmaxf(acc, 0.f));
}

// ---------------- fused layer2: root+bias + agg + softmax -> out ------------------
__global__ __launch_bounds__(256) void fused2(
    const int* __restrict__ off, const unsigned* __restrict__ sorted,
    const float* __restrict__ scales, const ushort* __restrict__ Y2,
    const float* __restrict__ b2, float* __restrict__ out) {
  int w = threadIdx.x >> 6, lane = threadIdx.x & 63;
  int d = blockIdx.x * 4 + w;
  int j = lane & 31, half = lane >> 5;
  int s0 = off[d], s1 = off[d + 1];
  float acc = 0.f;
  for (int i = s0 + half; i < s1; i += 2) {
    unsigned p = sorted[i];
    acc += bfu(Y2[(size_t)(p & 0xFFFF) * 544 + 32 + (p >> 16) * 32 + j]) * scales[i];
  }
  acc += __shfl_xor(acc, 32);
  float v = acc + bfu(Y2[(size_t)d * 544 + j]) + b2[j];
  float mx = v;
#pragma unroll
  for (int o = 16; o; o >>= 1) mx = fmaxf(mx, __shfl_xor(mx, o));
  float e = __expf(v - mx);
  float sum = e;
#pragma unroll
  for (int o = 16; o; o >>= 1) sum += __shfl_xor(sum, o);
  if (half == 0) out[(size_t)d * 32 + j] = e / sum;
}

// =================================================================================
extern "C" void kernel_launch(void* const* d_in, const int* in_sizes, int n_in,
                              void* d_out, int out_size, void* d_ws, size_t ws_size,
                              hipStream_t stream) {
  (void)in_sizes; (void)n_in; (void)out_size; (void)ws_size;
  const float* emb   = (const float*)d_in[0];
  const float* ipw   = (const float*)d_in[1];
  const float* ipb   = (const float*)d_in[2];
  const float* opw   = (const float*)d_in[3];
  const float* opb   = (const float*)d_in[4];
  const float* w1    = (const float*)d_in[5];
  const float* root1 = (const float*)d_in[6];
  const float* b1    = (const float*)d_in[7];
  const float* w2    = (const float*)d_in[8];
  const float* root2 = (const float*)d_in[9];
  const float* b2    = (const float*)d_in[10];
  const int*   eidx  = (const int*)d_in[11];
  const int*   etype = (const int*)d_in[12];
  const int* srcp = eidx;
  const int* dstp = eidx + NEDGE;

  unsigned char* ws = (unsigned char*)d_ws;
  size_t off_b = 0;
  auto alloc = [&](size_t bytes) {
    unsigned char* p = ws + off_b;
    off_b += (bytes + 255) & ~(size_t)255;
    return p;
  };

  // Region R reused sequentially: qkv 153.6MB -> Y1 108.8MB -> Y2 54.4MB
  unsigned char* R = alloc(153600000);
  __hip_bfloat16* qkv = (__hip_bfloat16*)R;
  __hip_bfloat16* Y1  = (__hip_bfloat16*)R;
  __hip_bfloat16* Y2  = (__hip_bfloat16*)R;
  __hip_bfloat16* o0  = (__hip_bfloat16*)alloc(12800000);
  __hip_bfloat16* x0  = (__hip_bfloat16*)alloc(12800000);
  __hip_bfloat16* x1b = (__hip_bfloat16*)alloc(6400000);
  int*            cnt = (int*)alloc(3200000);
  int*            offs = (int*)alloc((NNODES + 1) * 4);
  int*            fill = (int*)alloc(NNODES * 4);
  int*            part = (int*)alloc(SCAN_NB * 4);
  unsigned*       sorted = (unsigned*)alloc(NEDGE * 4);
  float*          scales = (float*)alloc(NEDGE * 4);
  __hip_bfloat16* BTqkv = (__hip_bfloat16*)alloc(98304);
  __hip_bfloat16* BTout = (__hip_bfloat16*)alloc(32768);
  __hip_bfloat16* BT1   = (__hip_bfloat16*)alloc(278528);
  __hip_bfloat16* BT2   = (__hip_bfloat16*)alloc(69632);

  // 1) weight prep + CSR build
  prep_weights<<<dim3((241664 + 255) / 256), dim3(256), 0, stream>>>(
      ipw, opw, w1, root1, w2, root2, BTqkv, BTout, BT1, BT2);
  hipMemsetAsync(cnt, 0, (size_t)RREL * NNODES * sizeof(int), stream);
  hipMemsetAsync(fill, 0, (size_t)NNODES * sizeof(int), stream);
  count_edges<<<dim3((NEDGE + 255) / 256), dim3(256), 0, stream>>>(dstp, etype, cnt);
  scan1<<<dim3(SCAN_NB), dim3(256), 0, stream>>>(cnt, offs, part);
  scan2<<<dim3(1), dim3(256), 0, stream>>>(part);
  scan3<<<dim3(SCAN_NB), dim3(256), 0, stream>>>(offs, part);
  scatter_edges<<<dim3((NEDGE + 255) / 256), dim3(256), 0, stream>>>(
      srcp, dstp, etype, cnt, offs, fill, sorted, scales);

  // 2) QKV (strip-loop): (200000 x 128 f32) @ (128 x 384) -> qkv
  qkv_gemm<<<dim3(1563), dim3(256), 0, stream>>>(emb, BTqkv, ipb, qkv);

  // 3) attention -> o0
  attn_kernel<<<dim3(25000), dim3(256), 0, stream>>>(qkv, o0);

  // 4) out_proj -> x0
  gemm_mfma<128, false><<<dim3(391, 1), dim3(256), 0, stream>>>(
      o0, BTout, opb, x0, NNODES, 128, 128, 128);

  // 5) Y1 = x0 @ [root1 | W1_r]: (50000 x 128) @ (128 x 1088)
  gemm_mfma<128, false><<<dim3(391, 9), dim3(256), 0, stream>>>(
      x0, BT1, nullptr, Y1, NNODES, 1088, 128, 1088);

  // 6) fused layer1 -> x1b
  fused1<<<dim3(NNODES / 4), dim3(256), 0, stream>>>(
      offs, sorted, scales, (const ushort*)Y1, b1, x1b);

  // 7) Y2 = x1b @ [root2 | W2_r]: (50000 x 64) @ (64 x 544)
  gemm_mfma<64, false><<<dim3(391, 5), dim3(256), 0, stream>>>(
      x1b, BT2, nullptr, Y2, NNODES, 544, 64, 544);

  // 8) fused layer2 + softmax -> out
  fused2<<<dim3(NNODES / 4), dim3(256), 0, stream>>>(
      offs, sorted, scales, (const ushort*)Y2, b2, (float*)d_out);
}